// Round 7
// baseline (187.917 us; speedup 1.0000x reference)
//
#include <hip/hip_runtime.h>
#include <math.h>

// TripletLoss N=8192, D=128, labels in [0,512). Round 7: back to the CLEAN
// R3 skeleton (no LDS staging — every LDS-staged variant R4-R6 produced
// 100-190 MB of phantom scratch HBM traffic; R3 was clean at FETCH 8.5 MB /
// WRITE 2 MB). Fix R3's real problem — latency-serial j-stream with too few
// waves — with raw TLP:
//   - 32 i-rows per wave (2 subs): bfrag 64->32 VGPRs.
//   - JSPLIT 64, grid 64x64 = 4096 blocks = 16K waves (3+ occupancy
//     rotations; L2 latency hidden by wave switching, not pipelining).
//   - launch_bounds(256,4): reg cap 128, demand ~100 -> no spill possible.
//   - No LDS, no barriers, no atomics in pair.
// Math (as R3, absmax was 0.0): u = dot(x_j,x_i) - 0.5*sq_j via MFMA
// 16x16x32 bf16, acc init = -0.5*sq_j (fp32, exact). hardest_pos(d^2 max)
// = min u over positives (self masked to +inf on wave-uniform diagonal
// tile), hardest_neg(d^2 min) = max u over negatives; d^2 = sq_i - 2u in
// reduce (monotone). valid row <=> (min_u < inf && max_u > -inf) == ref mask.

#define NROWS 8192
#define DIM   128
#define JSPLIT 64
#define JCHUNK (NROWS / JSPLIT)   // 128 j per y-block
#define NITER  (JCHUNK / 16)      // 8 j-tiles, even
#define IBLK   128                // i-rows per block (32 per wave)

typedef short bf16x8 __attribute__((ext_vector_type(8)));
typedef float f32x4  __attribute__((ext_vector_type(4)));

static __device__ __forceinline__ unsigned short f2bf(float f) {
    unsigned u = __float_as_uint(f);
    unsigned r = (u + 0x7FFFu + ((u >> 16) & 1u)) >> 16;   // RNE
    return (unsigned short)r;
}

__global__ __launch_bounds__(256) void prep_kernel(
    const float* __restrict__ x, float* __restrict__ sq,
    unsigned short* __restrict__ xb) {
    int t = blockIdx.x * 256 + threadIdx.x;
    int row = t >> 5;
    int c = t & 31;
    float4 v = ((const float4*)x)[t];
    float ps = v.x * v.x + v.y * v.y + v.z * v.z + v.w * v.w;
#pragma unroll
    for (int s = 1; s < 32; s <<= 1) ps += __shfl_xor(ps, s, 64);
    if (c == 0) sq[row] = ps;
    ushort4 ob;
    ob.x = f2bf(v.x); ob.y = f2bf(v.y); ob.z = f2bf(v.z); ob.w = f2bf(v.w);
    ((ushort4*)xb)[t] = ob;
}

__global__ __launch_bounds__(256, 4) void pair_kernel(
    const unsigned short* __restrict__ xb, const float* __restrict__ sq,
    const int* __restrict__ labels,
    float* __restrict__ hpp, float* __restrict__ hnp) {
    const int lane = threadIdx.x & 63;
    const int wid = threadIdx.x >> 6;        // 0..3
    const int q = lane >> 4;                 // 0..3
    const int r = lane & 15;
    const int ibase = blockIdx.x * IBLK + wid * 32;
    const int jbase = blockIdx.y * JCHUNK;

    // B-frags (i side): B[n=r][k=ks*32+q*8..], resident for the whole j-loop.
    bf16x8 bfrag[2][4];
    int labi[2];
#pragma unroll
    for (int sub = 0; sub < 2; ++sub) {
        int irow = ibase + sub * 16 + r;
        labi[sub] = labels[irow];
#pragma unroll
        for (int ks = 0; ks < 4; ++ks)
            bfrag[sub][ks] = *(const bf16x8*)(xb + (size_t)irow * DIM + ks * 32 + q * 8);
    }

    float hp[2] = {INFINITY, INFINITY};     // min u over positives
    float hn[2] = {-INFINITY, -INFINITY};   // max u over negatives

    // Named ping-pong register sets — no dynamically indexed locals, no LDS.
    bf16x8 aP0, aP1, aP2, aP3, aQ0, aQ1, aQ2, aQ3;
    f32x4 sqjP, sqjQ;
    int4 labjP, labjQ;

#define GLOADP(j16) do { \
        const unsigned short* ap = xb + (size_t)((j16) + r) * DIM + q * 8; \
        aP0 = *(const bf16x8*)(ap); \
        aP1 = *(const bf16x8*)(ap + 32); \
        aP2 = *(const bf16x8*)(ap + 64); \
        aP3 = *(const bf16x8*)(ap + 96); \
        sqjP = *(const f32x4*)(sq + (j16) + q * 4); \
        labjP = *(const int4*)(labels + (j16) + q * 4); \
    } while (0)
#define GLOADQ(j16) do { \
        const unsigned short* ap = xb + (size_t)((j16) + r) * DIM + q * 8; \
        aQ0 = *(const bf16x8*)(ap); \
        aQ1 = *(const bf16x8*)(ap + 32); \
        aQ2 = *(const bf16x8*)(ap + 64); \
        aQ3 = *(const bf16x8*)(ap + 96); \
        sqjQ = *(const f32x4*)(sq + (j16) + q * 4); \
        labjQ = *(const int4*)(labels + (j16) + q * 4); \
    } while (0)
#define COMPUTE(a0, a1, a2, a3, sqj, labj, j16) do { \
        f32x4 cinit; \
        cinit[0] = -0.5f * (sqj)[0]; cinit[1] = -0.5f * (sqj)[1]; \
        cinit[2] = -0.5f * (sqj)[2]; cinit[3] = -0.5f * (sqj)[3]; \
        _Pragma("unroll") \
        for (int sub = 0; sub < 2; ++sub) { \
            f32x4 acc = cinit; \
            acc = __builtin_amdgcn_mfma_f32_16x16x32_bf16(a0, bfrag[sub][0], acc, 0, 0, 0); \
            acc = __builtin_amdgcn_mfma_f32_16x16x32_bf16(a1, bfrag[sub][1], acc, 0, 0, 0); \
            acc = __builtin_amdgcn_mfma_f32_16x16x32_bf16(a2, bfrag[sub][2], acc, 0, 0, 0); \
            acc = __builtin_amdgcn_mfma_f32_16x16x32_bf16(a3, bfrag[sub][3], acc, 0, 0, 0); \
            const int li = labi[sub]; \
            float u0 = acc[0], u1 = acc[1], u2 = acc[2], u3 = acc[3]; \
            float p0 = u0, p1 = u1, p2 = u2, p3 = u3; \
            if ((j16) == ibase + sub * 16) {  /* wave-uniform diagonal tile */ \
                int d = r - 4 * q;            /* self element: reg == d */ \
                p0 = (d == 0) ? INFINITY : p0; \
                p1 = (d == 1) ? INFINITY : p1; \
                p2 = (d == 2) ? INFINITY : p2; \
                p3 = (d == 3) ? INFINITY : p3; \
            } \
            hp[sub] = fminf(hp[sub], ((labj).x == li) ? p0 : INFINITY); \
            hn[sub] = fmaxf(hn[sub], ((labj).x == li) ? -INFINITY : u0); \
            hp[sub] = fminf(hp[sub], ((labj).y == li) ? p1 : INFINITY); \
            hn[sub] = fmaxf(hn[sub], ((labj).y == li) ? -INFINITY : u1); \
            hp[sub] = fminf(hp[sub], ((labj).z == li) ? p2 : INFINITY); \
            hn[sub] = fmaxf(hn[sub], ((labj).z == li) ? -INFINITY : u2); \
            hp[sub] = fminf(hp[sub], ((labj).w == li) ? p3 : INFINITY); \
            hn[sub] = fmaxf(hn[sub], ((labj).w == li) ? -INFINITY : u3); \
        } \
    } while (0)

    GLOADP(jbase);
#pragma unroll
    for (int jt = 0; jt < NITER; jt += 2) {
        GLOADQ(jbase + (jt + 1) * 16);
        COMPUTE(aP0, aP1, aP2, aP3, sqjP, labjP, jbase + jt * 16);
        if (jt + 2 < NITER) GLOADP(jbase + (jt + 2) * 16);
        COMPUTE(aQ0, aQ1, aQ2, aQ3, sqjQ, labjQ, jbase + (jt + 1) * 16);
    }
#undef GLOADP
#undef GLOADQ
#undef COMPUTE

    // reduce across the 4 q-groups (lanes r, r+16, r+32, r+48)
#pragma unroll
    for (int sub = 0; sub < 2; ++sub) {
        hp[sub] = fminf(hp[sub], __shfl_xor(hp[sub], 16, 64));
        hp[sub] = fminf(hp[sub], __shfl_xor(hp[sub], 32, 64));
        hn[sub] = fmaxf(hn[sub], __shfl_xor(hn[sub], 16, 64));
        hn[sub] = fmaxf(hn[sub], __shfl_xor(hn[sub], 32, 64));
    }
    if (lane < 16) {
        const int pbase = blockIdx.y * NROWS;
#pragma unroll
        for (int sub = 0; sub < 2; ++sub) {
            int irow = ibase + sub * 16 + lane;
            hpp[pbase + irow] = hp[sub];
            hnp[pbase + irow] = hn[sub];
        }
    }
}

__global__ __launch_bounds__(256) void reduce_kernel(
    const float* __restrict__ hpp, const float* __restrict__ hnp,
    const float* __restrict__ sq,
    float* __restrict__ rsum, float* __restrict__ rcnt) {
    int row = blockIdx.x * 256 + threadIdx.x;
    float mnp = INFINITY, mxn = -INFINITY;
#pragma unroll 8
    for (int p = 0; p < JSPLIT; ++p) {
        mnp = fminf(mnp, hpp[p * NROWS + row]);
        mxn = fmaxf(mxn, hnp[p * NROWS + row]);
    }
    float s = sq[row];
    float sum = 0.f, cnt = 0.f;
    if (mnp < INFINITY && mxn > -INFINITY) {   // == reference valid mask
        float dp = sqrtf(fmaxf(s - 2.f * mnp, 1e-12f));
        float dn = sqrtf(fmaxf(s - 2.f * mxn, 1e-12f));
        sum = fmaxf(dp - dn + 0.3f, 1e-6f);
        cnt = 1.f;
    }
#pragma unroll
    for (int sh = 1; sh < 64; sh <<= 1) {
        sum += __shfl_xor(sum, sh, 64);
        cnt += __shfl_xor(cnt, sh, 64);
    }
    __shared__ float ss[4], sc[4];
    int w = threadIdx.x >> 6;
    if ((threadIdx.x & 63) == 0) { ss[w] = sum; sc[w] = cnt; }
    __syncthreads();
    if (threadIdx.x == 0) {
        rsum[blockIdx.x] = ss[0] + ss[1] + ss[2] + ss[3];
        rcnt[blockIdx.x] = sc[0] + sc[1] + sc[2] + sc[3];
    }
}

__global__ void final_kernel(const float* __restrict__ rsum,
                             const float* __restrict__ rcnt,
                             float* __restrict__ out) {
    int t = threadIdx.x;   // 64 threads
    float s = (t < 32) ? rsum[t] : 0.f;
    float c = (t < 32) ? rcnt[t] : 0.f;
#pragma unroll
    for (int sh = 1; sh < 64; sh <<= 1) {
        s += __shfl_xor(s, sh, 64);
        c += __shfl_xor(c, sh, 64);
    }
    if (t == 0) out[0] = (c > 0.f) ? s / c : 0.f;
}

extern "C" void kernel_launch(void* const* d_in, const int* in_sizes, int n_in,
                              void* d_out, int out_size, void* d_ws, size_t ws_size,
                              hipStream_t stream) {
    const float* x = (const float*)d_in[0];
    const int* labels = (const int*)d_in[1];
    float* out = (float*)d_out;

    // ws layout (16-B aligned):
    //   sq   @ 0        (32 KB)
    //   rsum @ 32768 (128 B), rcnt @ 33024 (128 B)
    //   hpp  @ 36864    (2 MB)  [JSPLIT x NROWS], fully written by pair
    //   hnp  @ 2134016  (2 MB)
    //   xb   @ 4231168  (2 MB bf16)      total ~6.3 MB
    char* ws = (char*)d_ws;
    float* sq = (float*)ws;
    float* rsum = (float*)(ws + 32768);
    float* rcnt = (float*)(ws + 33024);
    float* hpp = (float*)(ws + 36864);
    float* hnp = (float*)(ws + 2134016);
    unsigned short* xb = (unsigned short*)(ws + 4231168);

    prep_kernel<<<(NROWS * 32) / 256, 256, 0, stream>>>(x, sq, xb);
    pair_kernel<<<dim3(NROWS / IBLK, JSPLIT), 256, 0, stream>>>(xb, sq, labels, hpp, hnp);
    reduce_kernel<<<NROWS / 256, 256, 0, stream>>>(hpp, hnp, sq, rsum, rcnt);
    final_kernel<<<1, 64, 0, stream>>>(rsum, rcnt, out);
}

// Round 8
// 146.302 us; speedup vs baseline: 1.2844x; 1.2844x over previous
//
#include <hip/hip_runtime.h>
#include <math.h>

// TripletLoss N=8192, D=128, labels in [0,512). Round 8: R7 with ONE change.
// ROOT CAUSE of R4-R7's 100-266 MB phantom HBM traffic: the second
// __launch_bounds__ argument. (256,3)/(256,4) cap the ARCH-VGPR half at
// 84/64 regs; this kernel needs ~90-100 arch VGPRs -> everything above the
// cap spilled to scratch each j-iter. R2/R3 (plain (256)) were clean.
// Evidence: VGPR_Count pinned exactly at the cap (84/64) in every spilling
// round; clean rounds allocated 72/96 freely.
//   => pair_kernel now __launch_bounds__(256) with NO min-waves clamp.
// Everything else identical to R7:
//   - 32 i-rows per wave (2 subs), JSPLIT 64, grid 64x64 = 4096 blocks.
//   - register ping-pong j-stream, no LDS, no barriers, no atomics.
//   - u = dot - 0.5*sq_j via MFMA 16x16x32 bf16 (acc init = -0.5*sq_j).
//     hardest_pos = min u over positives (self masked on diag tile),
//     hardest_neg = max u over negatives; d^2 = sq_i - 2u in reduce.
//     valid <=> (min_u < inf && max_u > -inf) == reference mask.

#define NROWS 8192
#define DIM   128
#define JSPLIT 64
#define JCHUNK (NROWS / JSPLIT)   // 128 j per y-block
#define NITER  (JCHUNK / 16)      // 8 j-tiles, even
#define IBLK   128                // i-rows per block (32 per wave)

typedef short bf16x8 __attribute__((ext_vector_type(8)));
typedef float f32x4  __attribute__((ext_vector_type(4)));

static __device__ __forceinline__ unsigned short f2bf(float f) {
    unsigned u = __float_as_uint(f);
    unsigned r = (u + 0x7FFFu + ((u >> 16) & 1u)) >> 16;   // RNE
    return (unsigned short)r;
}

__global__ __launch_bounds__(256) void prep_kernel(
    const float* __restrict__ x, float* __restrict__ sq,
    unsigned short* __restrict__ xb) {
    int t = blockIdx.x * 256 + threadIdx.x;
    int row = t >> 5;
    int c = t & 31;
    float4 v = ((const float4*)x)[t];
    float ps = v.x * v.x + v.y * v.y + v.z * v.z + v.w * v.w;
#pragma unroll
    for (int s = 1; s < 32; s <<= 1) ps += __shfl_xor(ps, s, 64);
    if (c == 0) sq[row] = ps;
    ushort4 ob;
    ob.x = f2bf(v.x); ob.y = f2bf(v.y); ob.z = f2bf(v.z); ob.w = f2bf(v.w);
    ((ushort4*)xb)[t] = ob;
}

__global__ __launch_bounds__(256) void pair_kernel(
    const unsigned short* __restrict__ xb, const float* __restrict__ sq,
    const int* __restrict__ labels,
    float* __restrict__ hpp, float* __restrict__ hnp) {
    const int lane = threadIdx.x & 63;
    const int wid = threadIdx.x >> 6;        // 0..3
    const int q = lane >> 4;                 // 0..3
    const int r = lane & 15;
    const int ibase = blockIdx.x * IBLK + wid * 32;
    const int jbase = blockIdx.y * JCHUNK;

    // B-frags (i side): B[n=r][k=ks*32+q*8..], resident for the whole j-loop.
    bf16x8 bfrag[2][4];
    int labi[2];
#pragma unroll
    for (int sub = 0; sub < 2; ++sub) {
        int irow = ibase + sub * 16 + r;
        labi[sub] = labels[irow];
#pragma unroll
        for (int ks = 0; ks < 4; ++ks)
            bfrag[sub][ks] = *(const bf16x8*)(xb + (size_t)irow * DIM + ks * 32 + q * 8);
    }

    float hp[2] = {INFINITY, INFINITY};     // min u over positives
    float hn[2] = {-INFINITY, -INFINITY};   // max u over negatives

    // Named ping-pong register sets — no dynamically indexed locals, no LDS.
    bf16x8 aP0, aP1, aP2, aP3, aQ0, aQ1, aQ2, aQ3;
    f32x4 sqjP, sqjQ;
    int4 labjP, labjQ;

#define GLOADP(j16) do { \
        const unsigned short* ap = xb + (size_t)((j16) + r) * DIM + q * 8; \
        aP0 = *(const bf16x8*)(ap); \
        aP1 = *(const bf16x8*)(ap + 32); \
        aP2 = *(const bf16x8*)(ap + 64); \
        aP3 = *(const bf16x8*)(ap + 96); \
        sqjP = *(const f32x4*)(sq + (j16) + q * 4); \
        labjP = *(const int4*)(labels + (j16) + q * 4); \
    } while (0)
#define GLOADQ(j16) do { \
        const unsigned short* ap = xb + (size_t)((j16) + r) * DIM + q * 8; \
        aQ0 = *(const bf16x8*)(ap); \
        aQ1 = *(const bf16x8*)(ap + 32); \
        aQ2 = *(const bf16x8*)(ap + 64); \
        aQ3 = *(const bf16x8*)(ap + 96); \
        sqjQ = *(const f32x4*)(sq + (j16) + q * 4); \
        labjQ = *(const int4*)(labels + (j16) + q * 4); \
    } while (0)
#define COMPUTE(a0, a1, a2, a3, sqj, labj, j16) do { \
        f32x4 cinit; \
        cinit[0] = -0.5f * (sqj)[0]; cinit[1] = -0.5f * (sqj)[1]; \
        cinit[2] = -0.5f * (sqj)[2]; cinit[3] = -0.5f * (sqj)[3]; \
        _Pragma("unroll") \
        for (int sub = 0; sub < 2; ++sub) { \
            f32x4 acc = cinit; \
            acc = __builtin_amdgcn_mfma_f32_16x16x32_bf16(a0, bfrag[sub][0], acc, 0, 0, 0); \
            acc = __builtin_amdgcn_mfma_f32_16x16x32_bf16(a1, bfrag[sub][1], acc, 0, 0, 0); \
            acc = __builtin_amdgcn_mfma_f32_16x16x32_bf16(a2, bfrag[sub][2], acc, 0, 0, 0); \
            acc = __builtin_amdgcn_mfma_f32_16x16x32_bf16(a3, bfrag[sub][3], acc, 0, 0, 0); \
            const int li = labi[sub]; \
            float u0 = acc[0], u1 = acc[1], u2 = acc[2], u3 = acc[3]; \
            float p0 = u0, p1 = u1, p2 = u2, p3 = u3; \
            if ((j16) == ibase + sub * 16) {  /* wave-uniform diagonal tile */ \
                int d = r - 4 * q;            /* self element: reg == d */ \
                p0 = (d == 0) ? INFINITY : p0; \
                p1 = (d == 1) ? INFINITY : p1; \
                p2 = (d == 2) ? INFINITY : p2; \
                p3 = (d == 3) ? INFINITY : p3; \
            } \
            hp[sub] = fminf(hp[sub], ((labj).x == li) ? p0 : INFINITY); \
            hn[sub] = fmaxf(hn[sub], ((labj).x == li) ? -INFINITY : u0); \
            hp[sub] = fminf(hp[sub], ((labj).y == li) ? p1 : INFINITY); \
            hn[sub] = fmaxf(hn[sub], ((labj).y == li) ? -INFINITY : u1); \
            hp[sub] = fminf(hp[sub], ((labj).z == li) ? p2 : INFINITY); \
            hn[sub] = fmaxf(hn[sub], ((labj).z == li) ? -INFINITY : u2); \
            hp[sub] = fminf(hp[sub], ((labj).w == li) ? p3 : INFINITY); \
            hn[sub] = fmaxf(hn[sub], ((labj).w == li) ? -INFINITY : u3); \
        } \
    } while (0)

    GLOADP(jbase);
#pragma unroll
    for (int jt = 0; jt < NITER; jt += 2) {
        GLOADQ(jbase + (jt + 1) * 16);
        COMPUTE(aP0, aP1, aP2, aP3, sqjP, labjP, jbase + jt * 16);
        if (jt + 2 < NITER) GLOADP(jbase + (jt + 2) * 16);
        COMPUTE(aQ0, aQ1, aQ2, aQ3, sqjQ, labjQ, jbase + (jt + 1) * 16);
    }
#undef GLOADP
#undef GLOADQ
#undef COMPUTE

    // reduce across the 4 q-groups (lanes r, r+16, r+32, r+48)
#pragma unroll
    for (int sub = 0; sub < 2; ++sub) {
        hp[sub] = fminf(hp[sub], __shfl_xor(hp[sub], 16, 64));
        hp[sub] = fminf(hp[sub], __shfl_xor(hp[sub], 32, 64));
        hn[sub] = fmaxf(hn[sub], __shfl_xor(hn[sub], 16, 64));
        hn[sub] = fmaxf(hn[sub], __shfl_xor(hn[sub], 32, 64));
    }
    if (lane < 16) {
        const int pbase = blockIdx.y * NROWS;
#pragma unroll
        for (int sub = 0; sub < 2; ++sub) {
            int irow = ibase + sub * 16 + lane;
            hpp[pbase + irow] = hp[sub];
            hnp[pbase + irow] = hn[sub];
        }
    }
}

__global__ __launch_bounds__(256) void reduce_kernel(
    const float* __restrict__ hpp, const float* __restrict__ hnp,
    const float* __restrict__ sq,
    float* __restrict__ rsum, float* __restrict__ rcnt) {
    int row = blockIdx.x * 256 + threadIdx.x;
    float mnp = INFINITY, mxn = -INFINITY;
#pragma unroll 8
    for (int p = 0; p < JSPLIT; ++p) {
        mnp = fminf(mnp, hpp[p * NROWS + row]);
        mxn = fmaxf(mxn, hnp[p * NROWS + row]);
    }
    float s = sq[row];
    float sum = 0.f, cnt = 0.f;
    if (mnp < INFINITY && mxn > -INFINITY) {   // == reference valid mask
        float dp = sqrtf(fmaxf(s - 2.f * mnp, 1e-12f));
        float dn = sqrtf(fmaxf(s - 2.f * mxn, 1e-12f));
        sum = fmaxf(dp - dn + 0.3f, 1e-6f);
        cnt = 1.f;
    }
#pragma unroll
    for (int sh = 1; sh < 64; sh <<= 1) {
        sum += __shfl_xor(sum, sh, 64);
        cnt += __shfl_xor(cnt, sh, 64);
    }
    __shared__ float ss[4], sc[4];
    int w = threadIdx.x >> 6;
    if ((threadIdx.x & 63) == 0) { ss[w] = sum; sc[w] = cnt; }
    __syncthreads();
    if (threadIdx.x == 0) {
        rsum[blockIdx.x] = ss[0] + ss[1] + ss[2] + ss[3];
        rcnt[blockIdx.x] = sc[0] + sc[1] + sc[2] + sc[3];
    }
}

__global__ void final_kernel(const float* __restrict__ rsum,
                             const float* __restrict__ rcnt,
                             float* __restrict__ out) {
    int t = threadIdx.x;   // 64 threads
    float s = (t < 32) ? rsum[t] : 0.f;
    float c = (t < 32) ? rcnt[t] : 0.f;
#pragma unroll
    for (int sh = 1; sh < 64; sh <<= 1) {
        s += __shfl_xor(s, sh, 64);
        c += __shfl_xor(c, sh, 64);
    }
    if (t == 0) out[0] = (c > 0.f) ? s / c : 0.f;
}

extern "C" void kernel_launch(void* const* d_in, const int* in_sizes, int n_in,
                              void* d_out, int out_size, void* d_ws, size_t ws_size,
                              hipStream_t stream) {
    const float* x = (const float*)d_in[0];
    const int* labels = (const int*)d_in[1];
    float* out = (float*)d_out;

    // ws layout (16-B aligned):
    //   sq   @ 0        (32 KB)
    //   rsum @ 32768 (128 B), rcnt @ 33024 (128 B)
    //   hpp  @ 36864    (2 MB)  [JSPLIT x NROWS], fully written by pair
    //   hnp  @ 2134016  (2 MB)
    //   xb   @ 4231168  (2 MB bf16)      total ~6.3 MB
    char* ws = (char*)d_ws;
    float* sq = (float*)ws;
    float* rsum = (float*)(ws + 32768);
    float* rcnt = (float*)(ws + 33024);
    float* hpp = (float*)(ws + 36864);
    float* hnp = (float*)(ws + 2134016);
    unsigned short* xb = (unsigned short*)(ws + 4231168);

    prep_kernel<<<(NROWS * 32) / 256, 256, 0, stream>>>(x, sq, xb);
    pair_kernel<<<dim3(NROWS / IBLK, JSPLIT), 256, 0, stream>>>(xb, sq, labels, hpp, hnp);
    reduce_kernel<<<NROWS / 256, 256, 0, stream>>>(hpp, hnp, sq, rsum, rcnt);
    final_kernel<<<1, 64, 0, stream>>>(rsum, rcnt, out);
}